// Round 1
// baseline (251.949 us; speedup 1.0000x reference)
//
#include <hip/hip_runtime.h>
#include <stdint.h>

#define FH 45
#define FW 80
#define CIN 64
#define CF 64
#define NANCH 2784
#define BB 16
#define JP 80   // padded j dimension (75 real: 2 cls + 73 reg)
#define JN 75

// ---------------- k1: combined weights V[ci][y][jp], biasM[y][jp], offset table ----------------
// V[ci,y,j] = sum_c conv_w[c,ci] * W(c*45+y, j)   (W = [cls_w | reg_w])
// biasM[y,j] = sum_c conv_b[c] * W(c*45+y, j)
// off[n,y] = invalid[n,y] ? -1 : (y*FW + cut_xs[n,y]) * JP
__global__ __launch_bounds__(256) void k1_weights(
    const float* __restrict__ conv_w, const float* __restrict__ conv_b,
    const float* __restrict__ cls_w, const float* __restrict__ reg_w,
    const int* __restrict__ cut_xs, const uint8_t* __restrict__ invalid,
    float* __restrict__ V, float* __restrict__ biasM, int* __restrict__ off) {
    int idx = blockIdx.x * blockDim.x + threadIdx.x;
    const int NV = CIN * FH * JP;          // 230400
    const int NB = FH * JP;                // 3600
    const int NO = NANCH * FH;             // 125280
    if (idx < NV) {
        int j = idx % JP;
        int y = (idx / JP) % FH;
        int ci = idx / (JP * FH);
        float s = 0.f;
        if (j < JN) {
            if (j < 2) {
                for (int c = 0; c < CF; ++c)
                    s += conv_w[c * CIN + ci] * cls_w[(c * FH + y) * 2 + j];
            } else {
                for (int c = 0; c < CF; ++c)
                    s += conv_w[c * CIN + ci] * reg_w[(c * FH + y) * 73 + (j - 2)];
            }
        }
        V[idx] = s;
    } else if (idx < NV + NB) {
        int t = idx - NV;
        int j = t % JP;
        int y = t / JP;
        float s = 0.f;
        if (j < JN) {
            if (j < 2) {
                for (int c = 0; c < CF; ++c)
                    s += conv_b[c] * cls_w[(c * FH + y) * 2 + j];
            } else {
                for (int c = 0; c < CF; ++c)
                    s += conv_b[c] * reg_w[(c * FH + y) * 73 + (j - 2)];
            }
        }
        biasM[t] = s;
    } else if (idx < NV + NB + NO) {
        int t = idx - NV - NB;
        int y = t % FH;
        off[t] = invalid[t] ? -1 : (y * FW + cut_xs[t]) * JP;
    }
}

// ---------------- k2: M[b][y][x][jp] = sum_ci x[b,ci,y,x]*V[ci,y,j] + biasM[y,j] ----------------
// one block per (b,y); LDS-stage x row-slab (64x80) and V slab (64x80); 4x8 register tile.
__global__ __launch_bounds__(256) void k2_feat(
    const float* __restrict__ x, const float* __restrict__ V,
    const float* __restrict__ biasM, float* __restrict__ M) {
    int b = blockIdx.x / FH;
    int y = blockIdx.x % FH;
    __shared__ float xl[CIN * FW];   // 20 KB
    __shared__ float vl[CIN * JP];   // 20 KB
    __shared__ float bl[JP];
    int tid = threadIdx.x;
    for (int t = tid; t < CIN * FW; t += 256) {
        int ci = t / FW, xc = t % FW;
        xl[t] = x[((b * CIN + ci) * FH + y) * FW + xc];
    }
    for (int t = tid; t < CIN * JP; t += 256) {
        vl[t] = V[t / JP * (FH * JP) + y * JP + (t % JP)];
    }
    if (tid < JP) bl[tid] = biasM[y * JP + tid];
    __syncthreads();
    if (tid < 200) {                  // 20 x-groups(4) x 10 j-groups(8)
        int tx = tid % 20;
        int tj = tid / 20;
        int x0 = tx * 4, j0 = tj * 8;
        float acc[4][8];
        for (int xx = 0; xx < 4; ++xx)
            for (int jj = 0; jj < 8; ++jj)
                acc[xx][jj] = bl[j0 + jj];
        for (int ci = 0; ci < CIN; ++ci) {
            float4 xv = *reinterpret_cast<const float4*>(&xl[ci * FW + x0]);
            float4 v0 = *reinterpret_cast<const float4*>(&vl[ci * JP + j0]);
            float4 v1 = *reinterpret_cast<const float4*>(&vl[ci * JP + j0 + 4]);
            float xa[4] = {xv.x, xv.y, xv.z, xv.w};
            float va[8] = {v0.x, v0.y, v0.z, v0.w, v1.x, v1.y, v1.z, v1.w};
            for (int xx = 0; xx < 4; ++xx)
                for (int jj = 0; jj < 8; ++jj)
                    acc[xx][jj] = fmaf(xa[xx], va[jj], acc[xx][jj]);
        }
        float* mbase = M + (((size_t)b * FH + y) * FW) * JP;
        for (int xx = 0; xx < 4; ++xx) {
            float* row = mbase + (size_t)(x0 + xx) * JP + j0;
            *reinterpret_cast<float4*>(row)     = make_float4(acc[xx][0], acc[xx][1], acc[xx][2], acc[xx][3]);
            *reinterpret_cast<float4*>(row + 4) = make_float4(acc[xx][4], acc[xx][5], acc[xx][6], acc[xx][7]);
        }
    }
}

// ---------------- k3: gather-sum over 45 y's + epilogue ----------------
// thread = (b, n, j) with j in [0,75); out[b,n,77]
__global__ __launch_bounds__(256) void k3_gather(
    const float* __restrict__ M, const float* __restrict__ anchors,
    const float* __restrict__ cls_b, const float* __restrict__ reg_b,
    const int* __restrict__ off, float* __restrict__ out) {
    int idx = blockIdx.x * blockDim.x + threadIdx.x;
    const int TOT = BB * NANCH * JN;
    if (idx >= TOT) return;
    int j = idx % JN;
    int bn = idx / JN;
    int n = bn % NANCH;
    int b = bn / NANCH;
    const int* orow = off + n * FH;
    const float* mb = M + (size_t)b * (FH * FW * JP) + j;
    float s = 0.f;
    #pragma unroll
    for (int y = 0; y < FH; ++y) {
        int o = orow[y];
        if (o >= 0) s += mb[o];
    }
    float* dst = out + (size_t)bn * 77;
    const float* arow = anchors + (size_t)n * 77;
    if (j < 2) {
        dst[j] = s + cls_b[j];
        dst[j + 2] = arow[j + 2];      // p24 passthrough
    } else {
        dst[j + 2] = s + reg_b[j - 2] + arow[j + 2];
    }
}

extern "C" void kernel_launch(void* const* d_in, const int* in_sizes, int n_in,
                              void* d_out, int out_size, void* d_ws, size_t ws_size,
                              hipStream_t stream) {
    const float* x       = (const float*)d_in[0];
    const float* conv_w  = (const float*)d_in[1];
    const float* conv_b  = (const float*)d_in[2];
    const float* cls_w   = (const float*)d_in[3];
    const float* cls_b   = (const float*)d_in[4];
    const float* reg_w   = (const float*)d_in[5];
    const float* reg_b   = (const float*)d_in[6];
    const float* anchors = (const float*)d_in[7];
    const int* cut_xs    = (const int*)d_in[8];
    const uint8_t* invalid = (const uint8_t*)d_in[9];
    float* out = (float*)d_out;

    float* V     = (float*)d_ws;                         // 230400 f
    float* biasM = V + CIN * FH * JP;                    // 3600 f
    float* M     = biasM + FH * JP;                      // 4,608,000 f
    int*   off   = (int*)(M + (size_t)BB * FH * FW * JP); // 125280 i

    int n1 = CIN * FH * JP + FH * JP + NANCH * FH;
    k1_weights<<<(n1 + 255) / 256, 256, 0, stream>>>(conv_w, conv_b, cls_w, reg_w,
                                                     cut_xs, invalid, V, biasM, off);
    k2_feat<<<BB * FH, 256, 0, stream>>>(x, V, biasM, M);
    int n3 = BB * NANCH * JN;
    k3_gather<<<(n3 + 255) / 256, 256, 0, stream>>>(M, anchors, cls_b, reg_b, off, out);
}

// Round 2
// 151.256 us; speedup vs baseline: 1.6657x; 1.6657x over previous
//
#include <hip/hip_runtime.h>
#include <stdint.h>

#define FH 45
#define FW 80
#define CIN 64
#define CF 64
#define NANCH 2784
#define BB 16
#define JP 80            // padded j dimension (75 real: 2 cls + 73 reg)
#define JN 75
#define MROW (FH * FW)   // 3600 rows per batch
#define SB ((MROW + 1) * JP)   // per-batch M stride, +1 dummy zero row
#define ZOFF (MROW * JP)       // offset of the zero row within a batch
#define TOTBN (BB * NANCH)

// ---------------- k1: combined weights V[y][ci][j], biasM[y][j], offset table ----------------
// Blocks 0..89: (y, jhalf) mini-GEMM with LDS-staged conv_w + W slab.
// Blocks 90+ : off[n,y] = invalid ? ZOFF : (y*FW + cut_xs[n,y]) * JP
__global__ __launch_bounds__(256) void k1_weights(
    const float* __restrict__ conv_w, const float* __restrict__ conv_b,
    const float* __restrict__ cls_w, const float* __restrict__ reg_w,
    const int* __restrict__ cut_xs, const uint8_t* __restrict__ invalid,
    float* __restrict__ V, float* __restrict__ biasM, int* __restrict__ off) {
    int blk = blockIdx.x;
    int tid = threadIdx.x;
    if (blk >= 90) {
        int idx = (blk - 90) * 256 + tid;
        if (idx < NANCH * FH) {
            int y = idx % FH;
            off[idx] = invalid[idx] ? ZOFF : (y * FW + cut_xs[idx]) * JP;
        }
        return;
    }
    int y = blk >> 1;
    int j0 = (blk & 1) * 40;
    __shared__ float cw[CF * CIN];   // conv_w[c][ci], contiguous copy (16 KB)
    __shared__ float wl[CF * 40];    // W[c*45+y][j0+jl], zero-padded (10 KB)
    __shared__ float cb[CF];
    for (int i = tid; i < CF * CIN; i += 256) cw[i] = conv_w[i];
    if (tid < CF) cb[tid] = conv_b[tid];
    for (int i = tid; i < CF * 40; i += 256) {
        int c = i / 40, jl = i % 40, j = j0 + jl;
        float v = 0.f;
        if (j < 2) v = cls_w[(c * FH + y) * 2 + j];
        else if (j < JN) v = reg_w[(c * FH + y) * 73 + (j - 2)];
        wl[i] = v;
    }
    __syncthreads();
    int ci = tid & 63;
    int jb = tid >> 6;               // 0..3
    float acc[10];
    #pragma unroll
    for (int k = 0; k < 10; ++k) acc[k] = 0.f;
    for (int c = 0; c < CF; ++c) {
        float a = cw[c * CIN + ci];
        #pragma unroll
        for (int k = 0; k < 10; ++k)
            acc[k] = fmaf(a, wl[c * 40 + jb + 4 * k], acc[k]);
    }
    #pragma unroll
    for (int k = 0; k < 10; ++k)
        V[y * (CIN * JP) + ci * JP + j0 + jb + 4 * k] = acc[k];
    if (tid < 40) {
        float s = 0.f;
        for (int c = 0; c < CF; ++c) s += cb[c] * wl[c * 40 + tid];
        biasM[y * JP + j0 + tid] = s;
    }
}

// ---------------- k2: M[b][(y*FW+x)][j] = sum_ci x[b,ci,y,x]*V[y,ci,j] + biasM[y,j] ----------------
__global__ __launch_bounds__(256) void k2_feat(
    const float* __restrict__ x, const float* __restrict__ V,
    const float* __restrict__ biasM, float* __restrict__ M) {
    int b = blockIdx.x / FH;
    int y = blockIdx.x % FH;
    __shared__ float xl[CIN * FW];   // 20 KB
    __shared__ float vl[CIN * JP];   // 20 KB
    __shared__ float bl[JP];
    int tid = threadIdx.x;
    for (int t = tid; t < CIN * FW; t += 256) {
        int ci = t / FW, xc = t % FW;
        xl[t] = x[((b * CIN + ci) * FH + y) * FW + xc];
    }
    const float* vsrc = V + y * (CIN * JP);
    for (int t = tid; t < CIN * JP; t += 256) vl[t] = vsrc[t];   // contiguous
    if (tid < JP) bl[tid] = biasM[y * JP + tid];
    // zero the per-batch dummy row once (y==0 blocks)
    if (y == 0 && tid < JP) M[(size_t)b * SB + ZOFF + tid] = 0.f;
    __syncthreads();
    if (tid < 200) {                  // 20 x-groups(4) x 10 j-groups(8)
        int tx = tid % 20;
        int tj = tid / 20;
        int x0 = tx * 4, jg0 = tj * 8;
        float acc[4][8];
        for (int xx = 0; xx < 4; ++xx)
            for (int jj = 0; jj < 8; ++jj)
                acc[xx][jj] = bl[jg0 + jj];
        for (int ci = 0; ci < CIN; ++ci) {
            float4 xv = *reinterpret_cast<const float4*>(&xl[ci * FW + x0]);
            float4 v0 = *reinterpret_cast<const float4*>(&vl[ci * JP + jg0]);
            float4 v1 = *reinterpret_cast<const float4*>(&vl[ci * JP + jg0 + 4]);
            float xa[4] = {xv.x, xv.y, xv.z, xv.w};
            float va[8] = {v0.x, v0.y, v0.z, v0.w, v1.x, v1.y, v1.z, v1.w};
            for (int xx = 0; xx < 4; ++xx)
                for (int jj = 0; jj < 8; ++jj)
                    acc[xx][jj] = fmaf(xa[xx], va[jj], acc[xx][jj]);
        }
        float* mbase = M + (size_t)b * SB + ((size_t)y * FW) * JP;
        for (int xx = 0; xx < 4; ++xx) {
            float* row = mbase + (size_t)(x0 + xx) * JP + jg0;
            *reinterpret_cast<float4*>(row)     = make_float4(acc[xx][0], acc[xx][1], acc[xx][2], acc[xx][3]);
            *reinterpret_cast<float4*>(row + 4) = make_float4(acc[xx][4], acc[xx][5], acc[xx][6], acc[xx][7]);
        }
    }
}

// ---------------- k3: gather-sum over 45 y's + epilogue ----------------
// block = 13 anchors x 19 j-groups (float4). Offsets LDS-staged, branch-free.
#define BNB 13
__global__ __launch_bounds__(256) void k3_gather(
    const float* __restrict__ M, const float* __restrict__ anchors,
    const float* __restrict__ cls_b, const float* __restrict__ reg_b,
    const int* __restrict__ off, float* __restrict__ out) {
    __shared__ int sidx[BNB * FH];
    int tid = threadIdx.x;
    int bn0 = blockIdx.x * BNB;
    for (int i = tid; i < BNB * FH; i += 256) {
        int bnl = i / FH, y = i % FH;
        int bn = bn0 + bnl;
        sidx[i] = (bn < TOTBN) ? off[(bn % NANCH) * FH + y] : ZOFF;
    }
    __syncthreads();
    if (tid >= BNB * 19) return;
    int lb = tid / 19;
    int jg = tid % 19;
    int bn = bn0 + lb;
    if (bn >= TOTBN) return;
    int b = bn / NANCH;
    int n = bn % NANCH;
    const float* mb = M + (size_t)b * SB + jg * 4;
    const int* si = sidx + lb * FH;
    float4 s = make_float4(0.f, 0.f, 0.f, 0.f);
    #pragma unroll
    for (int y = 0; y < FH; ++y) {
        int o = si[y];
        float4 v = *reinterpret_cast<const float4*>(mb + o);
        s.x += v.x; s.y += v.y; s.z += v.z; s.w += v.w;
    }
    float sa[4] = {s.x, s.y, s.z, s.w};
    float* dst = out + (size_t)bn * 77;
    const float* arow = anchors + (size_t)n * 77;
    int j0 = jg * 4;
    #pragma unroll
    for (int e = 0; e < 4; ++e) {
        int j = j0 + e;
        if (j < 2)       dst[j]     = sa[e] + cls_b[j];
        else if (j < JN) dst[j + 2] = sa[e] + reg_b[j - 2] + arow[j + 2];
    }
    if (jg == 0) { dst[2] = arow[2]; dst[3] = arow[3]; }
}

extern "C" void kernel_launch(void* const* d_in, const int* in_sizes, int n_in,
                              void* d_out, int out_size, void* d_ws, size_t ws_size,
                              hipStream_t stream) {
    const float* x       = (const float*)d_in[0];
    const float* conv_w  = (const float*)d_in[1];
    const float* conv_b  = (const float*)d_in[2];
    const float* cls_w   = (const float*)d_in[3];
    const float* cls_b   = (const float*)d_in[4];
    const float* reg_w   = (const float*)d_in[5];
    const float* reg_b   = (const float*)d_in[6];
    const float* anchors = (const float*)d_in[7];
    const int* cut_xs    = (const int*)d_in[8];
    const uint8_t* invalid = (const uint8_t*)d_in[9];
    float* out = (float*)d_out;

    float* V     = (float*)d_ws;                          // FH*CIN*JP = 230400 f
    float* biasM = V + FH * CIN * JP;                     // 3600 f
    float* M     = biasM + FH * JP;                       // BB*SB f
    int*   off   = (int*)(M + (size_t)BB * SB);           // NANCH*FH i

    int n_off_blocks = (NANCH * FH + 255) / 256;          // 490
    k1_weights<<<90 + n_off_blocks, 256, 0, stream>>>(conv_w, conv_b, cls_w, reg_w,
                                                      cut_xs, invalid, V, biasM, off);
    k2_feat<<<BB * FH, 256, 0, stream>>>(x, V, biasM, M);
    int nblk3 = (TOTBN + BNB - 1) / BNB;                  // 3427
    k3_gather<<<nblk3, 256, 0, stream>>>(M, anchors, cls_b, reg_b, off, out);
}

// Round 4
// 141.932 us; speedup vs baseline: 1.7751x; 1.0657x over previous
//
#include <hip/hip_runtime.h>
#include <hip/hip_bf16.h>
#include <stdint.h>

#define FH 45
#define FW 80
#define CIN 64
#define CF 64
#define NANCH 2784
#define BB 16
#define JP 80            // padded j dimension (75 real: 2 cls + 73 reg)
#define JN 75
#define MROW (FH * FW)         // 3600 rows per batch
#define SB ((MROW + 1) * JP)   // per-batch M stride in ELEMENTS, +1 dummy zero row
#define ZOFF (MROW * JP)       // element offset of the zero row within a batch
#define TOTBN (BB * NANCH)
#define ANB 25                 // anchors per k3 block
#define CPB ((NANCH + ANB - 1) / ANB)   // 112 chunks per batch

static __device__ __forceinline__ uint32_t pkbf(float a, float b) {
    uint32_t lo = (uint32_t)__bfloat16_as_ushort(__float2bfloat16(a));
    uint32_t hi = (uint32_t)__bfloat16_as_ushort(__float2bfloat16(b));
    return lo | (hi << 16);
}

// ---------------- k1: V[y][ci][j] (f32), biasM[y][j], offset table ----------------
__global__ __launch_bounds__(256) void k1_weights(
    const float* __restrict__ conv_w, const float* __restrict__ conv_b,
    const float* __restrict__ cls_w, const float* __restrict__ reg_w,
    const int* __restrict__ cut_xs, const uint8_t* __restrict__ invalid,
    float* __restrict__ V, float* __restrict__ biasM, int* __restrict__ off) {
    int blk = blockIdx.x;
    int tid = threadIdx.x;
    if (blk >= 90) {
        int idx = (blk - 90) * 256 + tid;
        if (idx < NANCH * FH) {
            int y = idx % FH;
            off[idx] = invalid[idx] ? ZOFF : (y * FW + cut_xs[idx]) * JP;
        }
        return;
    }
    int y = blk >> 1;
    int j0 = (blk & 1) * 40;
    __shared__ float cw[CF * CIN];   // 16 KB
    __shared__ float wl[CF * 40];    // 10 KB
    __shared__ float cb[CF];
    for (int i = tid; i < CF * CIN; i += 256) cw[i] = conv_w[i];
    if (tid < CF) cb[tid] = conv_b[tid];
    for (int i = tid; i < CF * 40; i += 256) {
        int c = i / 40, jl = i % 40, j = j0 + jl;
        float v = 0.f;
        if (j < 2) v = cls_w[(c * FH + y) * 2 + j];
        else if (j < JN) v = reg_w[(c * FH + y) * 73 + (j - 2)];
        wl[i] = v;
    }
    __syncthreads();
    int ci = tid & 63;
    int jb = tid >> 6;               // 0..3
    float acc[10];
    #pragma unroll
    for (int k = 0; k < 10; ++k) acc[k] = 0.f;
    for (int c = 0; c < CF; ++c) {
        float a = cw[c * CIN + ci];
        #pragma unroll
        for (int k = 0; k < 10; ++k)
            acc[k] = fmaf(a, wl[c * 40 + jb + 4 * k], acc[k]);
    }
    #pragma unroll
    for (int k = 0; k < 10; ++k)
        V[y * (CIN * JP) + ci * JP + j0 + jb + 4 * k] = acc[k];
    if (tid < 40) {
        float s = 0.f;
        for (int c = 0; c < CF; ++c) s += cb[c] * wl[c * 40 + tid];
        biasM[y * JP + j0 + tid] = s;
    }
}

// ---------------- k2: M[b][(y*FW+x)][j] (bf16) = sum_ci x*V + biasM ----------------
__global__ __launch_bounds__(256) void k2_feat(
    const float* __restrict__ x, const float* __restrict__ V,
    const float* __restrict__ biasM, __hip_bfloat16* __restrict__ M) {
    int b = blockIdx.x / FH;
    int y = blockIdx.x % FH;
    __shared__ float xl[CIN * FW];   // 20 KB
    __shared__ float vl[CIN * JP];   // 20 KB
    __shared__ float bl[JP];
    int tid = threadIdx.x;
    for (int t = tid; t < CIN * FW; t += 256) {
        int ci = t / FW, xc = t % FW;
        xl[t] = x[((b * CIN + ci) * FH + y) * FW + xc];
    }
    const float* vsrc = V + y * (CIN * JP);
    for (int t = tid; t < CIN * JP; t += 256) vl[t] = vsrc[t];
    if (tid < JP) bl[tid] = biasM[y * JP + tid];
    __hip_bfloat16* Mb = M + (size_t)b * SB;
    if (y == 0 && tid < JP) Mb[ZOFF + tid] = __float2bfloat16(0.f);  // dummy zero row
    __syncthreads();
    if (tid < 200) {                  // 20 x-groups(4) x 10 j-groups(8)
        int tx = tid % 20;
        int tj = tid / 20;
        int x0 = tx * 4, jg0 = tj * 8;
        float acc[4][8];
        for (int xx = 0; xx < 4; ++xx)
            for (int jj = 0; jj < 8; ++jj)
                acc[xx][jj] = bl[jg0 + jj];
        for (int ci = 0; ci < CIN; ++ci) {
            float4 xv = *reinterpret_cast<const float4*>(&xl[ci * FW + x0]);
            float4 v0 = *reinterpret_cast<const float4*>(&vl[ci * JP + jg0]);
            float4 v1 = *reinterpret_cast<const float4*>(&vl[ci * JP + jg0 + 4]);
            float xa[4] = {xv.x, xv.y, xv.z, xv.w};
            float va[8] = {v0.x, v0.y, v0.z, v0.w, v1.x, v1.y, v1.z, v1.w};
            for (int xx = 0; xx < 4; ++xx)
                for (int jj = 0; jj < 8; ++jj)
                    acc[xx][jj] = fmaf(xa[xx], va[jj], acc[xx][jj]);
        }
        __hip_bfloat16* mbase = Mb + ((size_t)y * FW) * JP;
        for (int xx = 0; xx < 4; ++xx) {
            uint32_t* row = (uint32_t*)(mbase + (size_t)(x0 + xx) * JP + jg0);
            uint4 pk;
            pk.x = pkbf(acc[xx][0], acc[xx][1]);
            pk.y = pkbf(acc[xx][2], acc[xx][3]);
            pk.z = pkbf(acc[xx][4], acc[xx][5]);
            pk.w = pkbf(acc[xx][6], acc[xx][7]);
            *reinterpret_cast<uint4*>(row) = pk;
        }
    }
}

// ---------------- k3: gather-sum over 45 y's (bf16 M) + epilogue ----------------
// block = ANB anchors x 10 j-groups (8 j each, uint4 of bf16x8). XCD-swizzled by b.
__global__ __launch_bounds__(256) void k3_gather(
    const __hip_bfloat16* __restrict__ M, const float* __restrict__ anchors,
    const float* __restrict__ cls_b, const float* __restrict__ reg_b,
    const int* __restrict__ off, float* __restrict__ out) {
    __shared__ int sidx[ANB * FH];   // 4.5 KB
    int tid = threadIdx.x;
    // swizzle: XCD (= wgid%8) owns batches {2k, 2k+1} -> 1.15 MB of M per L2
    int wg = blockIdx.x;
    int b = (wg % 8) * 2 + ((wg >> 3) & 1);
    int chunk = wg >> 4;
    int n0 = chunk * ANB;
    int nvalid = NANCH - n0; if (nvalid > ANB) nvalid = ANB;
    for (int i = tid; i < ANB * FH; i += 256) {
        int nl = i / FH;
        sidx[i] = (nl < nvalid) ? off[n0 * FH + i] : ZOFF;
    }
    __syncthreads();
    if (tid >= ANB * 10) return;
    int lb = tid / 10;
    int jg = tid % 10;
    if (lb >= nvalid) return;
    int n = n0 + lb;
    const __hip_bfloat16* mb = M + (size_t)b * SB + jg * 8;
    const int* si = sidx + lb * FH;
    float s[8];
    #pragma unroll
    for (int e = 0; e < 8; ++e) s[e] = 0.f;
    #pragma unroll
    for (int y = 0; y < FH; ++y) {
        int o = si[y];
        uint4 v = *reinterpret_cast<const uint4*>(mb + o);
        uint32_t u[4] = {v.x, v.y, v.z, v.w};
        #pragma unroll
        for (int p = 0; p < 4; ++p) {
            s[2 * p]     += __uint_as_float(u[p] << 16);
            s[2 * p + 1] += __uint_as_float(u[p] & 0xFFFF0000u);
        }
    }
    float* dst = out + ((size_t)b * NANCH + n) * 77;
    const float* arow = anchors + (size_t)n * 77;
    int j0 = jg * 8;
    #pragma unroll
    for (int e = 0; e < 8; ++e) {
        int j = j0 + e;
        if (j < 2)       dst[j]     = s[e] + cls_b[j];
        else if (j < JN) dst[j + 2] = s[e] + reg_b[j - 2] + arow[j + 2];
    }
    if (jg == 0) { dst[2] = arow[2]; dst[3] = arow[3]; }
}

extern "C" void kernel_launch(void* const* d_in, const int* in_sizes, int n_in,
                              void* d_out, int out_size, void* d_ws, size_t ws_size,
                              hipStream_t stream) {
    const float* x       = (const float*)d_in[0];
    const float* conv_w  = (const float*)d_in[1];
    const float* conv_b  = (const float*)d_in[2];
    const float* cls_w   = (const float*)d_in[3];
    const float* cls_b   = (const float*)d_in[4];
    const float* reg_w   = (const float*)d_in[5];
    const float* reg_b   = (const float*)d_in[6];
    const float* anchors = (const float*)d_in[7];
    const int* cut_xs    = (const int*)d_in[8];
    const uint8_t* invalid = (const uint8_t*)d_in[9];
    float* out = (float*)d_out;

    float* V     = (float*)d_ws;                          // FH*CIN*JP f32
    float* biasM = V + FH * CIN * JP;                     // FH*JP f32
    __hip_bfloat16* M = (__hip_bfloat16*)(biasM + FH * JP);   // BB*SB bf16 (16B-aligned)
    int*   off   = (int*)((char*)M + (size_t)BB * SB * sizeof(__hip_bfloat16));

    int n_off_blocks = (NANCH * FH + 255) / 256;          // 490
    k1_weights<<<90 + n_off_blocks, 256, 0, stream>>>(conv_w, conv_b, cls_w, reg_w,
                                                      cut_xs, invalid, V, biasM, off);
    k2_feat<<<BB * FH, 256, 0, stream>>>(x, V, biasM, M);
    k3_gather<<<16 * CPB, 256, 0, stream>>>(M, anchors, cls_b, reg_b, off, out);
}